// Round 1
// baseline (118.701 us; speedup 1.0000x reference)
//
#include <hip/hip_runtime.h>

// Pendulum2 constrained-dynamics DAE forward, closed-form per row.
// m = [1, 50], l = [1, 1], g = 10  ->  minv = [1,1,0.02,0.02].
//
// Memory-bound (AI ~ 0.5 FLOP/B; roofline ~21 us at 6.3 TB/s for 128 MiB).
// Structure (Guideline 11 shape):
//   - grid capped at 2048 blocks, UNROLL=8 float4s per thread
//   - the 8 loads are independent and issued before any use -> MLP 8/thread
//   - chunk-strided indexing (j = base + k*NT + t): every load/store
//     instruction is unit-stride across the wave -> perfect coalescing
//   - plain (cached) stores: in+out = 128 MiB < 256 MiB L3, so let the
//     Infinity Cache absorb traffic across harness iterations
// Per-pair math: thread j holds one float4 (half-row); lane partner (j^1)
// holds the other half. __shfl_xor(1) gives both lanes the full row; both
// redundantly do the ~30-FLOP 2x2 constraint solve (free), then
//   even lane (j=2r)   writes velocities (passthrough)
//   odd  lane (j=2r+1) writes accelerations.
// Lane parity == float4-index parity since all strides are even.

typedef float vfloat4_t __attribute__((ext_vector_type(4)));

#define UNROLL 8

__device__ __forceinline__ float4 pend2_process(float4 mine, bool odd) {
    // Exchange with lane partner (lanes 2k / 2k+1).
    float4 other;
    other.x = __shfl_xor(mine.x, 1);
    other.y = __shfl_xor(mine.y, 1);
    other.z = __shfl_xor(mine.z, 1);
    other.w = __shfl_xor(mine.w, 1);

    float4 p = odd ? other : mine;   // x0, y0, x1, y1 (even float4 of the row)
    float4 q = odd ? mine : other;   // u0, w0, u1, w1 (odd  float4 of the row)

    float x0 = p.x, y0 = p.y, x1 = p.z, y1 = p.w;
    float u0 = q.x, w0 = q.y, u1 = q.z, w1 = q.w;

    float dx = x0 - x1, dy = y0 - y1;
    float du = u0 - u1, dw = w0 - w1;

    float L11 = 4.0f * (x0 * x0 + y0 * y0);
    float L12 = 4.0f * (x0 * dx + y0 * dy);
    float L22 = 4.08f * (dx * dx + dy * dy);   // 4 * (1 + 1/50) * |d|^2

    float R1 = -20.0f * y0 + 2.0f * (u0 * u0 + w0 * w0);
    float R2 = 2.0f * (du * du + dw * dw);     // gravity terms cancel exactly

    float det = L11 * L22 - L12 * L12;
    float inv = 1.0f / det;
    float lam1 = (L22 * R1 - L12 * R2) * inv;
    float lam2 = (L11 * R2 - L12 * R1) * inv;

    float4 res;
    if (odd) {
        res.x = -2.0f * (x0 * lam1 + dx * lam2);
        res.y = -10.0f - 2.0f * (y0 * lam1 + dy * lam2);
        res.z = 0.04f * dx * lam2;
        res.w = -10.0f + 0.04f * dy * lam2;
    } else {
        res = q;                     // velocity passthrough
    }
    return res;
}

__global__ __launch_bounds__(256) void pend2_dae_kernel(
    const float4* __restrict__ in,   // coords as float4s: [2*n_rows]
    float4* __restrict__ out,        // same layout
    int n4)                          // number of float4s = 2*n_rows
{
    const int NT  = gridDim.x * blockDim.x;          // total threads (even)
    const int t   = blockIdx.x * blockDim.x + threadIdx.x;
    const bool odd = (t & 1);  // == parity of every j this thread touches

    const int span  = NT * UNROLL;
    const int nfull = (n4 / span) * span;

    for (int base = 0; base < nfull; base += span) {
        float4 v[UNROLL];
        // 8 independent coalesced loads, all issued before first use.
        #pragma unroll
        for (int k = 0; k < UNROLL; ++k)
            v[k] = in[base + k * NT + t];

        #pragma unroll
        for (int k = 0; k < UNROLL; ++k) {
            float4 r = pend2_process(v[k], odd);
            out[base + k * NT + t] = r;
        }
    }

    // Generic tail (not taken at bs = 2097152: n4 = 4194304 = span * 2048/2048).
    for (int j = nfull + t; j < n4; j += NT) {
        float4 r = pend2_process(in[j], odd);
        out[j] = r;
    }
}

extern "C" void kernel_launch(void* const* d_in, const int* in_sizes, int n_in,
                              void* d_out, int out_size, void* d_ws, size_t ws_size,
                              hipStream_t stream) {
    // d_in[0] = t (unused, autonomous system), d_in[1] = coords [bs, 8] fp32
    const float4* coords = (const float4*)d_in[1];
    float4* out = (float4*)d_out;
    int n4 = in_sizes[1] / 4;   // total float4s (= 2 * batch rows)

    int block = 256;
    long long want = ((long long)n4 + (long long)block * UNROLL - 1)
                     / ((long long)block * UNROLL);
    int grid = (int)(want < 1 ? 1 : (want > 2048 ? 2048 : want));
    pend2_dae_kernel<<<grid, block, 0, stream>>>(coords, out, n4);
}